// Round 6
// baseline (256.924 us; speedup 1.0000x reference)
//
#include <hip/hip_runtime.h>
#include <hip/hip_bf16.h>

#define NDIM 2048
#define QDIM 1024
#define SDIM 512
#define NBINS 20

typedef __attribute__((ext_vector_type(8))) short bf16x8;
typedef __attribute__((ext_vector_type(4))) float f32x4;

__device__ __forceinline__ unsigned short f2bf(float f) {
  unsigned int u = __builtin_bit_cast(unsigned int, f);
  u += 0x7fffu + ((u >> 16) & 1u);   // RNE (no NaN in this data)
  return (unsigned short)(u >> 16);
}
__device__ __forceinline__ float bf2f(unsigned short h) {
  return __builtin_bit_cast(float, (unsigned int)h << 16);
}
// divide_no_nan(1, sqrt(x)) semantics
__device__ __forceinline__ float guard_rsqrt(float x) {
  return x > 0.f ? 1.0f / sqrtf(x) : 0.f;
}

// ---------------- K1: local calib (4 rows/block) + rowsum(shfl+atomic) + colsum(atomic)
__global__ __launch_bounds__(256) void k_calib(const float* __restrict__ graph,
                                               const float* __restrict__ calib_w,
                                               unsigned short* __restrict__ g0bf,
                                               float* __restrict__ rowsum,
                                               float* __restrict__ colsum) {
  __shared__ float sp[NBINS];
  int t = threadIdx.x;
  if (t == 0) {   // 20-bin softmax, recomputed per block (trivial)
    float m = -1e30f;
    for (int b = 0; b < NBINS; b++) m = fmaxf(m, calib_w[b]);
    float e[NBINS]; float s = 0.f;
    for (int b = 0; b < NBINS; b++) { e[b] = __expf(calib_w[b] - m); s += e[b]; }
    float inv = 1.0f / s;
    for (int b = 0; b < NBINS; b++) sp[b] = e[b] * inv;
  }
  __syncthreads();
  int r0 = blockIdx.x * 4;
  float colacc[8] = {0.f,0.f,0.f,0.f,0.f,0.f,0.f,0.f};
  #pragma unroll
  for (int r = 0; r < 4; r++) {
    int row = r0 + r;
    const float4* src = (const float4*)(graph + (size_t)row * NDIM);
    float4 in0 = src[t * 2];
    float4 in1 = src[t * 2 + 1];
    float gv[8] = {in0.x, in0.y, in0.z, in0.w, in1.x, in1.y, in1.z, in1.w};
    unsigned short ov[8];
    float rs = 0.f;
    #pragma unroll
    for (int i = 0; i < 8; i++) {
      float g = gv[i];
      float v = 0.f;
      if (g > 0.f) {
        // only bins within 2 of b*=round(19g) matter: z<5e-11 beyond
        int bstar = (int)floorf(g * 19.0f + 0.5f);
        int lo = bstar - 2;
        lo = lo < 0 ? 0 : (lo > NBINS - 5 ? NBINS - 5 : lo);
        float num = 0.f, den = 0.f;
        #pragma unroll
        for (int w = 0; w < 5; w++) {
          int b = lo + w;
          float d = g - (float)b * (1.0f / 19.0f);
          float z = __expf(-950.0f * d * d);   // sig = (1/19)/50 = 1/950 all bins
          den += z; num += z * sp[b];
        }
        v = den > 0.f ? num / den : 0.f;
      }
      ov[i] = f2bf(v);
      rs += v;
      colacc[i] += v;   // column index = t*8 + i (vectorized layout)
    }
    uint4 packed;
    __builtin_memcpy(&packed, ov, 16);
    *(uint4*)(g0bf + (size_t)row * NDIM + t * 8) = packed;
    // barrier-free wave reduction; 4 waves atomically combine per row
    #pragma unroll
    for (int m = 32; m > 0; m >>= 1) rs += __shfl_xor(rs, m);
    if ((t & 63) == 0) atomicAdd(&rowsum[row], rs);
  }
  #pragma unroll
  for (int i = 0; i < 8; i++) atomicAdd(&colsum[t * 8 + i], colacc[i]);   // FIX: match t*8+i load layout
}

// ---------------- K2: Bt[s][k] = g0[k][sid[s]] * mvec'[k], factors inline (pointwise!)
// mvec'[k] = guard_rsqrt(rowsum[k]) * guard_rsqrt(colsum[k]) * exp(col_w[k])
// (global softmax normalizer N/sum(exp) cancels: the global-calib stage is
// scale-invariant — gn=(g-mean)/std, mask sign-preserved, final row-normalize)
__global__ __launch_bounds__(256) void k_gatherBt(const unsigned short* __restrict__ g0bf,
                                                  const int* __restrict__ sid,
                                                  const float* __restrict__ rowsum,
                                                  const float* __restrict__ colsum,
                                                  const float* __restrict__ col_w,
                                                  unsigned short* __restrict__ Bt) {
  int s = blockIdx.x, t = threadIdx.x;
  int col = sid[s];
  int k0 = t * 8;
  float4 rs0 = *(const float4*)(rowsum + k0);
  float4 rs1 = *(const float4*)(rowsum + k0 + 4);
  float4 cs0 = *(const float4*)(colsum + k0);
  float4 cs1 = *(const float4*)(colsum + k0 + 4);
  float4 w0 = *(const float4*)(col_w + k0);
  float4 w1 = *(const float4*)(col_w + k0 + 4);
  float rsv[8] = {rs0.x, rs0.y, rs0.z, rs0.w, rs1.x, rs1.y, rs1.z, rs1.w};
  float csv[8] = {cs0.x, cs0.y, cs0.z, cs0.w, cs1.x, cs1.y, cs1.z, cs1.w};
  float wv[8]  = {w0.x, w0.y, w0.z, w0.w, w1.x, w1.y, w1.z, w1.w};
  unsigned short ov[8];
  #pragma unroll
  for (int i = 0; i < 8; i++) {
    float mv = guard_rsqrt(rsv[i]) * guard_rsqrt(csv[i]) * __expf(wv[i]);
    float g = bf2f(g0bf[(size_t)(k0 + i) * NDIM + col]);
    ov[i] = f2bf(g * mv);
  }
  uint4 packed;
  __builtin_memcpy(&packed, ov, 16);
  *(uint4*)(Bt + (size_t)s * NDIM + k0) = packed;
}

// ---------------- K3: MFMA 16x16x32 bf16, A direct from g0 via qid, split-K 4 -> Cp
__global__ __launch_bounds__(256) void k_mfma(const unsigned short* __restrict__ g0bf,
                                              const unsigned short* __restrict__ Bt,
                                              const int* __restrict__ qid,
                                              float* __restrict__ Cp) {
  int t = threadIdx.x;
  int lane = t & 63;
  int wave = t >> 6;
  int m0 = blockIdx.y * 64 + (wave >> 1) * 32;
  int n0 = blockIdx.x * 64 + (wave & 1) * 32;
  int kc = blockIdx.z;
  int fr = lane & 15;            // A-row / B-col within 16-tile
  int kq = (lane >> 4) * 8;      // k-quad offset
  int qa0 = qid[m0 + fr];
  int qa1 = qid[m0 + 16 + fr];
  const unsigned short* Ap0 = g0bf + (size_t)qa0 * NDIM + kc * 512 + kq;
  const unsigned short* Ap1 = g0bf + (size_t)qa1 * NDIM + kc * 512 + kq;
  const unsigned short* Bp0 = Bt + (size_t)(n0 + fr) * NDIM + kc * 512 + kq;
  const unsigned short* Bp1 = Bp0 + (size_t)16 * NDIM;
  f32x4 acc00 = {0.f,0.f,0.f,0.f}, acc01 = acc00, acc10 = acc00, acc11 = acc00;
  #pragma unroll 4
  for (int i = 0; i < 16; i++) {
    int off = i * 32;
    bf16x8 a0 = *(const bf16x8*)(Ap0 + off);
    bf16x8 a1 = *(const bf16x8*)(Ap1 + off);
    bf16x8 b0 = *(const bf16x8*)(Bp0 + off);
    bf16x8 b1 = *(const bf16x8*)(Bp1 + off);
    acc00 = __builtin_amdgcn_mfma_f32_16x16x32_bf16(a0, b0, acc00, 0, 0, 0);
    acc01 = __builtin_amdgcn_mfma_f32_16x16x32_bf16(a0, b1, acc01, 0, 0, 0);
    acc10 = __builtin_amdgcn_mfma_f32_16x16x32_bf16(a1, b0, acc10, 0, 0, 0);
    acc11 = __builtin_amdgcn_mfma_f32_16x16x32_bf16(a1, b1, acc11, 0, 0, 0);
  }
  // C/D layout: col = lane&15, row = (lane>>4)*4 + reg   [m89-verified]
  float* Cb = Cp + ((size_t)kc << 19);   // kc * QDIM * SDIM
  int r0 = (lane >> 4) * 4;
  int c0 = lane & 15;
  #pragma unroll
  for (int r = 0; r < 4; r++) {
    Cb[(size_t)(m0 + r0 + r) * SDIM + n0 + c0]           = acc00[r];
    Cb[(size_t)(m0 + r0 + r) * SDIM + n0 + 16 + c0]      = acc01[r];
    Cb[(size_t)(m0 + 16 + r0 + r) * SDIM + n0 + c0]      = acc10[r];
    Cb[(size_t)(m0 + 16 + r0 + r) * SDIM + n0 + 16 + c0] = acc11[r];
  }
}

// ---------------- K4: reduce partials, apply factors (fp32, inline), diag mask, C + stats
__global__ void k_reduce_stats(const float* __restrict__ Cp,
                               const int* __restrict__ qid, const int* __restrict__ sid,
                               const float* __restrict__ rowsum, const float* __restrict__ colsum,
                               const float* __restrict__ col_w,
                               float* __restrict__ C, double* __restrict__ stats) {
  __shared__ float r1[256], r2[256]; __shared__ int rc[256];
  int t = threadIdx.x;
  int idx4 = blockIdx.x * 256 + t;                 // float4 index, 512 blocks
  const float4* Cp4 = (const float4*)Cp;
  const int STRIDE4 = QDIM * SDIM / 4;             // 131072
  float4 v = Cp4[idx4];
  float4 v1 = Cp4[idx4 + STRIDE4];
  float4 v2 = Cp4[idx4 + 2 * STRIDE4];
  float4 v3 = Cp4[idx4 + 3 * STRIDE4];
  v.x += v1.x + v2.x + v3.x; v.y += v1.y + v2.y + v3.y;
  v.z += v1.z + v2.z + v3.z; v.w += v1.w + v2.w + v3.w;
  int base = idx4 * 4;
  int q = base >> 9;
  int s0 = base & (SDIM - 1);
  int qv = qid[q];
  float lq = guard_rsqrt(rowsum[qv]);
  int4 sv = *(const int4*)(sid + s0);
  v.x *= lq * guard_rsqrt(colsum[sv.x]) * __expf(col_w[sv.x]);
  v.y *= lq * guard_rsqrt(colsum[sv.y]) * __expf(col_w[sv.y]);
  v.z *= lq * guard_rsqrt(colsum[sv.z]) * __expf(col_w[sv.z]);
  v.w *= lq * guard_rsqrt(colsum[sv.w]) * __expf(col_w[sv.w]);
  if (sv.x == qv) v.x = 0.f;
  if (sv.y == qv) v.y = 0.f;
  if (sv.z == qv) v.z = 0.f;
  if (sv.w == qv) v.w = 0.f;
  ((float4*)C)[idx4] = v;
  float s = 0.f, s2 = 0.f; int c = 0;
  float* vp = (float*)&v;
  #pragma unroll
  for (int p = 0; p < 4; p++) {
    float x = vp[p];
    if (x > 0.f) { s += x; s2 += x * x; c++; }
  }
  r1[t] = s; r2[t] = s2; rc[t] = c; __syncthreads();
  for (int st = 128; st > 0; st >>= 1) {
    if (t < st) { r1[t] += r1[t+st]; r2[t] += r2[t+st]; rc[t] += rc[t+st]; }
    __syncthreads();
  }
  if (t == 0) {
    atomicAdd(&stats[0], (double)r1[0]);
    atomicAdd(&stats[1], (double)r2[0]);
    atomicAdd(&stats[2], (double)rc[0]);
  }
}

// ---------------- K5: global calib + row-normalize (one block per query row)
__global__ void k_final(const float* __restrict__ C, const double* __restrict__ stats,
                        const float* __restrict__ gw, const float* __restrict__ gb,
                        float* __restrict__ out) {
  __shared__ float red[256];
  int q = blockIdx.x, t = threadIdx.x;
  double mean_d = stats[0] / stats[2];
  double var_d = stats[1] / stats[2] - mean_d * mean_d;
  float mean = (float)mean_d;
  float invstd = (float)(1.0 / sqrt(var_d));
  float w0 = gw[0], w1 = gw[1], w2 = gw[2], w3 = gw[3], w4 = gw[4], bb = gb[0];
  float vals[2]; float rs = 0.f;
  #pragma unroll
  for (int p = 0; p < 2; p++) {
    int s = t + p * 256;
    float x = C[(size_t)q * SDIM + s];
    float v = 0.f;
    if (x > 0.f) {
      float gn = (x - mean) * invstd;
      float m = fabsf(gn);
      float sgnsq = (m > 0.f) ? (gn / m) * sqrtf(m) : 0.f;  // sign(gn)*sqrt(|gn|)
      float acc = w0 * gn + w1 * sgnsq;
      float gm = gn * m; acc += w2 * gm;   // gn*|gn|
      gm *= m;           acc += w3 * gm;   // gn*|gn|^2
      gm *= m;           acc += w4 * gm;   // gn*|gn|^3
      acc += bb;
      v = (acc > 0.f ? acc : __expf(acc) - 1.f) + 1.f;  // elu + 1
    }
    vals[p] = v; rs += v;
  }
  red[t] = rs; __syncthreads();
  for (int st = 128; st > 0; st >>= 1) { if (t < st) red[t] += red[t+st]; __syncthreads(); }
  float tot = red[0];
  float inv = tot > 0.f ? 1.0f / tot : 0.f;   // divide_no_nan
  #pragma unroll
  for (int p = 0; p < 2; p++) {
    int s = t + p * 256;
    out[(size_t)q * SDIM + s] = vals[p] * inv;
  }
}

extern "C" void kernel_launch(void* const* d_in, const int* in_sizes, int n_in,
                              void* d_out, int out_size, void* d_ws, size_t ws_size,
                              hipStream_t stream) {
  const float* graph    = (const float*)d_in[0];
  const float* calib_w  = (const float*)d_in[1];
  const float* global_w = (const float*)d_in[2];
  const float* global_b = (const float*)d_in[3];
  const float* col_w    = (const float*)d_in[4];
  const int*   qid      = (const int*)d_in[5];
  const int*   sid      = (const int*)d_in[6];
  float* out = (float*)d_out;

  char* ws = (char*)d_ws;
  // zero-region (one tiny memset): colsum | rowsum | stats
  float*  colsum = (float*)(ws + 0);                 // 2048 f = 8 KiB
  float*  rowsum = (float*)(ws + 8192);              // 2048 f = 8 KiB
  double* stats  = (double*)(ws + 16384);            // 3 d
  unsigned short* g0bf = (unsigned short*)(ws + 65536);                  // N*N bf16 = 8 MiB
  unsigned short* Bt   = (unsigned short*)(ws + 65536 + 8388608);        // S*N bf16 = 2 MiB
  float*  Cp     = (float*)(ws + 65536 + 8388608 + 2097152);             // 4*Q*S f = 8 MiB
  float*  C      = (float*)(ws + 65536 + 8388608 + 2097152 + 8388608);   // Q*S f = 2 MiB

  hipMemsetAsync(ws, 0, 16448, stream);

  k_calib<<<NDIM / 4, 256, 0, stream>>>(graph, calib_w, g0bf, rowsum, colsum);
  k_gatherBt<<<SDIM, 256, 0, stream>>>(g0bf, sid, rowsum, colsum, col_w, Bt);
  k_mfma<<<dim3(SDIM / 64, QDIM / 64, 4), 256, 0, stream>>>(g0bf, Bt, qid, Cp);
  k_reduce_stats<<<QDIM * SDIM / 1024, 256, 0, stream>>>(Cp, qid, sid, rowsum, colsum, col_w, C, stats);
  k_final<<<QDIM, 256, 0, stream>>>(C, stats, global_w, global_b, out);
}

// Round 7
// 151.656 us; speedup vs baseline: 1.6941x; 1.6941x over previous
//
#include <hip/hip_runtime.h>
#include <hip/hip_bf16.h>

#define NDIM 2048
#define QDIM 1024
#define SDIM 512
#define NBINS 20

typedef __attribute__((ext_vector_type(8))) short bf16x8;
typedef __attribute__((ext_vector_type(4))) float f32x4;

__device__ __forceinline__ unsigned short f2bf(float f) {
  unsigned int u = __builtin_bit_cast(unsigned int, f);
  u += 0x7fffu + ((u >> 16) & 1u);   // RNE (no NaN in this data)
  return (unsigned short)(u >> 16);
}
__device__ __forceinline__ float bf2f(unsigned short h) {
  return __builtin_bit_cast(float, (unsigned int)h << 16);
}
// divide_no_nan(1, sqrt(x)) semantics
__device__ __forceinline__ float guard_rsqrt(float x) {
  return x > 0.f ? 1.0f / sqrtf(x) : 0.f;
}

// ---------------- K1: local calib (4 rows/block) + rowsum + colsum
// colsum flush goes through an LDS transpose so the global atomics are
// LANE-CONSECUTIVE (lanes of one instruction -> 4 cache lines, not 32).
// R6's t*8+i scatter was 8x the line-transactions -> 144us stall.
__global__ __launch_bounds__(256) void k_calib(const float* __restrict__ graph,
                                               const float* __restrict__ calib_w,
                                               unsigned short* __restrict__ g0bf,
                                               float* __restrict__ rowsum,
                                               float* __restrict__ colsum) {
  __shared__ float sp[NBINS];
  __shared__ float lcol[NDIM];   // 8 KiB: per-block column partials
  int t = threadIdx.x;
  if (t == 0) {   // 20-bin softmax, recomputed per block (trivial)
    float m = -1e30f;
    for (int b = 0; b < NBINS; b++) m = fmaxf(m, calib_w[b]);
    float e[NBINS]; float s = 0.f;
    for (int b = 0; b < NBINS; b++) { e[b] = __expf(calib_w[b] - m); s += e[b]; }
    float inv = 1.0f / s;
    for (int b = 0; b < NBINS; b++) sp[b] = e[b] * inv;
  }
  __syncthreads();
  int r0 = blockIdx.x * 4;
  float colacc[8] = {0.f,0.f,0.f,0.f,0.f,0.f,0.f,0.f};
  #pragma unroll
  for (int r = 0; r < 4; r++) {
    int row = r0 + r;
    const float4* src = (const float4*)(graph + (size_t)row * NDIM);
    float4 in0 = src[t * 2];
    float4 in1 = src[t * 2 + 1];
    float gv[8] = {in0.x, in0.y, in0.z, in0.w, in1.x, in1.y, in1.z, in1.w};
    unsigned short ov[8];
    float rs = 0.f;
    #pragma unroll
    for (int i = 0; i < 8; i++) {
      float g = gv[i];
      float v = 0.f;
      if (g > 0.f) {
        // only bins within 2 of b*=round(19g) matter: z<5e-11 beyond
        int bstar = (int)floorf(g * 19.0f + 0.5f);
        int lo = bstar - 2;
        lo = lo < 0 ? 0 : (lo > NBINS - 5 ? NBINS - 5 : lo);
        float num = 0.f, den = 0.f;
        #pragma unroll
        for (int w = 0; w < 5; w++) {
          int b = lo + w;
          float d = g - (float)b * (1.0f / 19.0f);
          float z = __expf(-950.0f * d * d);   // sig = (1/19)/50 = 1/950 all bins
          den += z; num += z * sp[b];
        }
        v = den > 0.f ? num / den : 0.f;
      }
      ov[i] = f2bf(v);
      rs += v;
      colacc[i] += v;   // column t*8 + i
    }
    uint4 packed;
    __builtin_memcpy(&packed, ov, 16);
    *(uint4*)(g0bf + (size_t)row * NDIM + t * 8) = packed;
    // barrier-free wave reduction; 4 waves atomically combine per row
    #pragma unroll
    for (int m = 32; m > 0; m >>= 1) rs += __shfl_xor(rs, m);
    if ((t & 63) == 0) atomicAdd(&rowsum[row], rs);
  }
  // stage to LDS (slot t*8+i owned solely by thread t), then flush transposed
  *(float4*)&lcol[t * 8]     = *(float4*)&colacc[0];
  *(float4*)&lcol[t * 8 + 4] = *(float4*)&colacc[4];
  __syncthreads();
  #pragma unroll
  for (int j = 0; j < 8; j++)
    atomicAdd(&colsum[j * 256 + t], lcol[j * 256 + t]);   // lane-consecutive
}

// ---------------- K2: Bt[s][k] = g0[k][sid[s]] * mvec'[k], factors inline (pointwise!)
// mvec'[k] = guard_rsqrt(rowsum[k]) * guard_rsqrt(colsum[k]) * exp(col_w[k])
// (global softmax normalizer N/sum(exp) cancels: the global-calib stage is
// scale-invariant — gn=(g-mean)/std, mask sign-preserved, final row-normalize)
__global__ __launch_bounds__(256) void k_gatherBt(const unsigned short* __restrict__ g0bf,
                                                  const int* __restrict__ sid,
                                                  const float* __restrict__ rowsum,
                                                  const float* __restrict__ colsum,
                                                  const float* __restrict__ col_w,
                                                  unsigned short* __restrict__ Bt) {
  int s = blockIdx.x, t = threadIdx.x;
  int col = sid[s];
  int k0 = t * 8;
  float4 rs0 = *(const float4*)(rowsum + k0);
  float4 rs1 = *(const float4*)(rowsum + k0 + 4);
  float4 cs0 = *(const float4*)(colsum + k0);
  float4 cs1 = *(const float4*)(colsum + k0 + 4);
  float4 w0 = *(const float4*)(col_w + k0);
  float4 w1 = *(const float4*)(col_w + k0 + 4);
  float rsv[8] = {rs0.x, rs0.y, rs0.z, rs0.w, rs1.x, rs1.y, rs1.z, rs1.w};
  float csv[8] = {cs0.x, cs0.y, cs0.z, cs0.w, cs1.x, cs1.y, cs1.z, cs1.w};
  float wv[8]  = {w0.x, w0.y, w0.z, w0.w, w1.x, w1.y, w1.z, w1.w};
  unsigned short ov[8];
  #pragma unroll
  for (int i = 0; i < 8; i++) {
    float mv = guard_rsqrt(rsv[i]) * guard_rsqrt(csv[i]) * __expf(wv[i]);
    float g = bf2f(g0bf[(size_t)(k0 + i) * NDIM + col]);
    ov[i] = f2bf(g * mv);
  }
  uint4 packed;
  __builtin_memcpy(&packed, ov, 16);
  *(uint4*)(Bt + (size_t)s * NDIM + k0) = packed;
}

// ---------------- K3: MFMA 16x16x32 bf16, A direct from g0 via qid, split-K 4 -> Cp
__global__ __launch_bounds__(256) void k_mfma(const unsigned short* __restrict__ g0bf,
                                              const unsigned short* __restrict__ Bt,
                                              const int* __restrict__ qid,
                                              float* __restrict__ Cp) {
  int t = threadIdx.x;
  int lane = t & 63;
  int wave = t >> 6;
  int m0 = blockIdx.y * 64 + (wave >> 1) * 32;
  int n0 = blockIdx.x * 64 + (wave & 1) * 32;
  int kc = blockIdx.z;
  int fr = lane & 15;            // A-row / B-col within 16-tile
  int kq = (lane >> 4) * 8;      // k-quad offset
  int qa0 = qid[m0 + fr];
  int qa1 = qid[m0 + 16 + fr];
  const unsigned short* Ap0 = g0bf + (size_t)qa0 * NDIM + kc * 512 + kq;
  const unsigned short* Ap1 = g0bf + (size_t)qa1 * NDIM + kc * 512 + kq;
  const unsigned short* Bp0 = Bt + (size_t)(n0 + fr) * NDIM + kc * 512 + kq;
  const unsigned short* Bp1 = Bp0 + (size_t)16 * NDIM;
  f32x4 acc00 = {0.f,0.f,0.f,0.f}, acc01 = acc00, acc10 = acc00, acc11 = acc00;
  #pragma unroll 4
  for (int i = 0; i < 16; i++) {
    int off = i * 32;
    bf16x8 a0 = *(const bf16x8*)(Ap0 + off);
    bf16x8 a1 = *(const bf16x8*)(Ap1 + off);
    bf16x8 b0 = *(const bf16x8*)(Bp0 + off);
    bf16x8 b1 = *(const bf16x8*)(Bp1 + off);
    acc00 = __builtin_amdgcn_mfma_f32_16x16x32_bf16(a0, b0, acc00, 0, 0, 0);
    acc01 = __builtin_amdgcn_mfma_f32_16x16x32_bf16(a0, b1, acc01, 0, 0, 0);
    acc10 = __builtin_amdgcn_mfma_f32_16x16x32_bf16(a1, b0, acc10, 0, 0, 0);
    acc11 = __builtin_amdgcn_mfma_f32_16x16x32_bf16(a1, b1, acc11, 0, 0, 0);
  }
  // C/D layout: col = lane&15, row = (lane>>4)*4 + reg   [m89-verified]
  float* Cb = Cp + ((size_t)kc << 19);   // kc * QDIM * SDIM
  int r0 = (lane >> 4) * 4;
  int c0 = lane & 15;
  #pragma unroll
  for (int r = 0; r < 4; r++) {
    Cb[(size_t)(m0 + r0 + r) * SDIM + n0 + c0]           = acc00[r];
    Cb[(size_t)(m0 + r0 + r) * SDIM + n0 + 16 + c0]      = acc01[r];
    Cb[(size_t)(m0 + 16 + r0 + r) * SDIM + n0 + c0]      = acc10[r];
    Cb[(size_t)(m0 + 16 + r0 + r) * SDIM + n0 + 16 + c0] = acc11[r];
  }
}

// ---------------- K4: reduce partials, apply factors (fp32, inline), diag mask, C + stats
__global__ void k_reduce_stats(const float* __restrict__ Cp,
                               const int* __restrict__ qid, const int* __restrict__ sid,
                               const float* __restrict__ rowsum, const float* __restrict__ colsum,
                               const float* __restrict__ col_w,
                               float* __restrict__ C, double* __restrict__ stats) {
  __shared__ float r1[256], r2[256]; __shared__ int rc[256];
  int t = threadIdx.x;
  int idx4 = blockIdx.x * 256 + t;                 // float4 index, 512 blocks
  const float4* Cp4 = (const float4*)Cp;
  const int STRIDE4 = QDIM * SDIM / 4;             // 131072
  float4 v = Cp4[idx4];
  float4 v1 = Cp4[idx4 + STRIDE4];
  float4 v2 = Cp4[idx4 + 2 * STRIDE4];
  float4 v3 = Cp4[idx4 + 3 * STRIDE4];
  v.x += v1.x + v2.x + v3.x; v.y += v1.y + v2.y + v3.y;
  v.z += v1.z + v2.z + v3.z; v.w += v1.w + v2.w + v3.w;
  int base = idx4 * 4;
  int q = base >> 9;
  int s0 = base & (SDIM - 1);
  int qv = qid[q];
  float lq = guard_rsqrt(rowsum[qv]);
  int4 sv = *(const int4*)(sid + s0);
  v.x *= lq * guard_rsqrt(colsum[sv.x]) * __expf(col_w[sv.x]);
  v.y *= lq * guard_rsqrt(colsum[sv.y]) * __expf(col_w[sv.y]);
  v.z *= lq * guard_rsqrt(colsum[sv.z]) * __expf(col_w[sv.z]);
  v.w *= lq * guard_rsqrt(colsum[sv.w]) * __expf(col_w[sv.w]);
  if (sv.x == qv) v.x = 0.f;
  if (sv.y == qv) v.y = 0.f;
  if (sv.z == qv) v.z = 0.f;
  if (sv.w == qv) v.w = 0.f;
  ((float4*)C)[idx4] = v;
  float s = 0.f, s2 = 0.f; int c = 0;
  float* vp = (float*)&v;
  #pragma unroll
  for (int p = 0; p < 4; p++) {
    float x = vp[p];
    if (x > 0.f) { s += x; s2 += x * x; c++; }
  }
  r1[t] = s; r2[t] = s2; rc[t] = c; __syncthreads();
  for (int st = 128; st > 0; st >>= 1) {
    if (t < st) { r1[t] += r1[t+st]; r2[t] += r2[t+st]; rc[t] += rc[t+st]; }
    __syncthreads();
  }
  if (t == 0) {
    atomicAdd(&stats[0], (double)r1[0]);
    atomicAdd(&stats[1], (double)r2[0]);
    atomicAdd(&stats[2], (double)rc[0]);
  }
}

// ---------------- K5: global calib + row-normalize (one block per query row)
__global__ void k_final(const float* __restrict__ C, const double* __restrict__ stats,
                        const float* __restrict__ gw, const float* __restrict__ gb,
                        float* __restrict__ out) {
  __shared__ float red[256];
  int q = blockIdx.x, t = threadIdx.x;
  double mean_d = stats[0] / stats[2];
  double var_d = stats[1] / stats[2] - mean_d * mean_d;
  float mean = (float)mean_d;
  float invstd = (float)(1.0 / sqrt(var_d));
  float w0 = gw[0], w1 = gw[1], w2 = gw[2], w3 = gw[3], w4 = gw[4], bb = gb[0];
  float vals[2]; float rs = 0.f;
  #pragma unroll
  for (int p = 0; p < 2; p++) {
    int s = t + p * 256;
    float x = C[(size_t)q * SDIM + s];
    float v = 0.f;
    if (x > 0.f) {
      float gn = (x - mean) * invstd;
      float m = fabsf(gn);
      float sgnsq = (m > 0.f) ? (gn / m) * sqrtf(m) : 0.f;  // sign(gn)*sqrt(|gn|)
      float acc = w0 * gn + w1 * sgnsq;
      float gm = gn * m; acc += w2 * gm;   // gn*|gn|
      gm *= m;           acc += w3 * gm;   // gn*|gn|^2
      gm *= m;           acc += w4 * gm;   // gn*|gn|^3
      acc += bb;
      v = (acc > 0.f ? acc : __expf(acc) - 1.f) + 1.f;  // elu + 1
    }
    vals[p] = v; rs += v;
  }
  red[t] = rs; __syncthreads();
  for (int st = 128; st > 0; st >>= 1) { if (t < st) red[t] += red[t+st]; __syncthreads(); }
  float tot = red[0];
  float inv = tot > 0.f ? 1.0f / tot : 0.f;   // divide_no_nan
  #pragma unroll
  for (int p = 0; p < 2; p++) {
    int s = t + p * 256;
    out[(size_t)q * SDIM + s] = vals[p] * inv;
  }
}

extern "C" void kernel_launch(void* const* d_in, const int* in_sizes, int n_in,
                              void* d_out, int out_size, void* d_ws, size_t ws_size,
                              hipStream_t stream) {
  const float* graph    = (const float*)d_in[0];
  const float* calib_w  = (const float*)d_in[1];
  const float* global_w = (const float*)d_in[2];
  const float* global_b = (const float*)d_in[3];
  const float* col_w    = (const float*)d_in[4];
  const int*   qid      = (const int*)d_in[5];
  const int*   sid      = (const int*)d_in[6];
  float* out = (float*)d_out;

  char* ws = (char*)d_ws;
  // zero-region (one tiny memset): colsum | rowsum | stats
  float*  colsum = (float*)(ws + 0);                 // 2048 f = 8 KiB
  float*  rowsum = (float*)(ws + 8192);              // 2048 f = 8 KiB
  double* stats  = (double*)(ws + 16384);            // 3 d
  unsigned short* g0bf = (unsigned short*)(ws + 65536);                  // N*N bf16 = 8 MiB
  unsigned short* Bt   = (unsigned short*)(ws + 65536 + 8388608);        // S*N bf16 = 2 MiB
  float*  Cp     = (float*)(ws + 65536 + 8388608 + 2097152);             // 4*Q*S f = 8 MiB
  float*  C      = (float*)(ws + 65536 + 8388608 + 2097152 + 8388608);   // Q*S f = 2 MiB

  hipMemsetAsync(ws, 0, 16448, stream);

  k_calib<<<NDIM / 4, 256, 0, stream>>>(graph, calib_w, g0bf, rowsum, colsum);
  k_gatherBt<<<SDIM, 256, 0, stream>>>(g0bf, sid, rowsum, colsum, col_w, Bt);
  k_mfma<<<dim3(SDIM / 64, QDIM / 64, 4), 256, 0, stream>>>(g0bf, Bt, qid, Cp);
  k_reduce_stats<<<QDIM * SDIM / 1024, 256, 0, stream>>>(Cp, qid, sid, rowsum, colsum, col_w, C, stats);
  k_final<<<QDIM, 256, 0, stream>>>(C, stats, global_w, global_b, out);
}

// Round 8
// 141.227 us; speedup vs baseline: 1.8192x; 1.0738x over previous
//
#include <hip/hip_runtime.h>
#include <hip/hip_bf16.h>

#define NDIM 2048
#define QDIM 1024
#define SDIM 512
#define NBINS 20
#define GT_TK 64
#define GT_TS 64

typedef __attribute__((ext_vector_type(8))) short bf16x8;
typedef __attribute__((ext_vector_type(4))) float f32x4;

__device__ __forceinline__ unsigned short f2bf(float f) {
  unsigned int u = __builtin_bit_cast(unsigned int, f);
  u += 0x7fffu + ((u >> 16) & 1u);   // RNE (no NaN in this data)
  return (unsigned short)(u >> 16);
}
__device__ __forceinline__ float bf2f(unsigned short h) {
  return __builtin_bit_cast(float, (unsigned int)h << 16);
}
// divide_no_nan(1, sqrt(x)) semantics
__device__ __forceinline__ float guard_rsqrt(float x) {
  return x > 0.f ? 1.0f / sqrtf(x) : 0.f;
}

// ---------------- K1: local calib (4 rows/block) + rowsum + colsum
// Gauss-ratio: z_w = K * r^w * q_w  (K cancels in num/den) -> 1 exp per element.
// colsum flushed via LDS transpose so global atomics are lane-consecutive.
__global__ __launch_bounds__(256) void k_calib(const float* __restrict__ graph,
                                               const float* __restrict__ calib_w,
                                               unsigned short* __restrict__ g0bf,
                                               float* __restrict__ rowsum,
                                               float* __restrict__ colsum) {
  __shared__ float sp[NBINS];
  __shared__ float lcol[NDIM];   // 8 KiB: per-block column partials
  int t = threadIdx.x;
  if (t == 0) {   // 20-bin softmax, recomputed per block (trivial)
    float m = -1e30f;
    for (int b = 0; b < NBINS; b++) m = fmaxf(m, calib_w[b]);
    float e[NBINS]; float s = 0.f;
    for (int b = 0; b < NBINS; b++) { e[b] = __expf(calib_w[b] - m); s += e[b]; }
    float inv = 1.0f / s;
    for (int b = 0; b < NBINS; b++) sp[b] = e[b] * inv;
  }
  __syncthreads();
  // q_w = exp(-950*w^2/361), w=0..4 (w=0 term is 1)
  const float q1 = __expf(-950.0f / 361.0f);
  const float q2 = __expf(-950.0f * 4.0f / 361.0f);
  const float q3 = __expf(-950.0f * 9.0f / 361.0f);
  const float q4 = __expf(-950.0f * 16.0f / 361.0f);
  int r0 = blockIdx.x * 4;
  float colacc[8] = {0.f,0.f,0.f,0.f,0.f,0.f,0.f,0.f};
  #pragma unroll
  for (int r = 0; r < 4; r++) {
    int row = r0 + r;
    const float4* src = (const float4*)(graph + (size_t)row * NDIM);
    float4 in0 = src[t * 2];
    float4 in1 = src[t * 2 + 1];
    float gv[8] = {in0.x, in0.y, in0.z, in0.w, in1.x, in1.y, in1.z, in1.w};
    unsigned short ov[8];
    float rs = 0.f;
    #pragma unroll
    for (int i = 0; i < 8; i++) {
      float g = gv[i];
      float v = 0.f;
      if (g > 0.f) {
        int bstar = (int)floorf(g * 19.0f + 0.5f);
        int lo = bstar - 2;
        lo = lo < 0 ? 0 : (lo > NBINS - 5 ? NBINS - 5 : lo);
        float delta = g - (float)lo * (1.0f / 19.0f);   // in [0, ~0.21]
        float rr = __expf(100.0f * delta);              // r^4 <= 3.7e36, safe
        float r2 = rr * rr;
        float r3 = r2 * rr;
        float r4 = r2 * r2;
        float den = 1.0f + q1 * rr + q2 * r2 + q3 * r3 + q4 * r4;
        float num = sp[lo] + q1 * rr * sp[lo+1] + q2 * r2 * sp[lo+2]
                  + q3 * r3 * sp[lo+3] + q4 * r4 * sp[lo+4];
        v = num / den;   // den >= 1
      }
      ov[i] = f2bf(v);
      rs += v;
      colacc[i] += v;   // column t*8 + i
    }
    uint4 packed;
    __builtin_memcpy(&packed, ov, 16);
    *(uint4*)(g0bf + (size_t)row * NDIM + t * 8) = packed;
    // barrier-free wave reduction; 4 waves atomically combine per row
    #pragma unroll
    for (int m = 32; m > 0; m >>= 1) rs += __shfl_xor(rs, m);
    if ((t & 63) == 0) atomicAdd(&rowsum[row], rs);
  }
  // stage to LDS (slot t*8+i owned solely by thread t), then flush transposed
  *(float4*)&lcol[t * 8]     = *(float4*)&colacc[0];
  *(float4*)&lcol[t * 8 + 4] = *(float4*)&colacc[4];
  __syncthreads();
  #pragma unroll
  for (int j = 0; j < 8; j++)
    atomicAdd(&colsum[j * 256 + t], lcol[j * 256 + t]);   // lane-consecutive
}

// ---------------- K2: Bt[s][k] = g0[k][sid[s]] * mvec'[k] * rightc'[sid[s]]
// Tiled LDS transpose: row-major g0 reads (gathers within one 4KB row),
// coalesced 256B Bt writes. rightc folded here (kills epilogue exps).
__global__ __launch_bounds__(512) void k_gatherBt(const unsigned short* __restrict__ g0bf,
                                                  const int* __restrict__ sid,
                                                  const float* __restrict__ rowsum,
                                                  const float* __restrict__ colsum,
                                                  const float* __restrict__ col_w,
                                                  unsigned short* __restrict__ Bt) {
  __shared__ int scol[GT_TS];
  __shared__ float lrsc[GT_TS];                       // rightc' per s
  __shared__ float lmv[GT_TK];                        // mvec' per k
  __shared__ unsigned short lt[GT_TS][GT_TK + 4];     // stride 68: 2-way banks, 8B-aligned rows
  int t = threadIdx.x;
  int k0 = blockIdx.x * GT_TK;   // 32 k-tiles
  int s0 = blockIdx.y * GT_TS;   // 8 s-tiles
  if (t < GT_TS) {
    int col = sid[s0 + t];
    scol[t] = col;
    lrsc[t] = guard_rsqrt(colsum[col]) * __expf(col_w[col]);
  } else if (t < GT_TS + GT_TK) {
    int k = k0 + t - GT_TS;
    lmv[t - GT_TS] = guard_rsqrt(rowsum[k]) * guard_rsqrt(colsum[k]) * __expf(col_w[k]);
  }
  __syncthreads();
  int tx = t & 63;        // s lane
  int ty = t >> 6;        // 0..7
  #pragma unroll
  for (int r = ty; r < GT_TK; r += 8) {
    float v = bf2f(g0bf[(size_t)(k0 + r) * NDIM + scol[tx]]);
    lt[tx][r] = f2bf(v * lmv[r] * lrsc[tx]);
  }
  __syncthreads();
  int s = t >> 3;             // 0..63
  int kk = (t & 7) * 8;       // 0..56
  uint4 val;
  __builtin_memcpy(&val, &lt[s][kk], 16);
  *(uint4*)(Bt + (size_t)(s0 + s) * NDIM + k0 + kk) = val;
}

// ---------------- K3: MFMA 16x16x32 bf16, A direct from g0 via qid, split-K 4 -> Cp
__global__ __launch_bounds__(256) void k_mfma(const unsigned short* __restrict__ g0bf,
                                              const unsigned short* __restrict__ Bt,
                                              const int* __restrict__ qid,
                                              float* __restrict__ Cp) {
  int t = threadIdx.x;
  int lane = t & 63;
  int wave = t >> 6;
  int m0 = blockIdx.y * 64 + (wave >> 1) * 32;
  int n0 = blockIdx.x * 64 + (wave & 1) * 32;
  int kc = blockIdx.z;
  int fr = lane & 15;            // A-row / B-col within 16-tile
  int kq = (lane >> 4) * 8;      // k-quad offset
  int qa0 = qid[m0 + fr];
  int qa1 = qid[m0 + 16 + fr];
  const unsigned short* Ap0 = g0bf + (size_t)qa0 * NDIM + kc * 512 + kq;
  const unsigned short* Ap1 = g0bf + (size_t)qa1 * NDIM + kc * 512 + kq;
  const unsigned short* Bp0 = Bt + (size_t)(n0 + fr) * NDIM + kc * 512 + kq;
  const unsigned short* Bp1 = Bp0 + (size_t)16 * NDIM;
  f32x4 acc00 = {0.f,0.f,0.f,0.f}, acc01 = acc00, acc10 = acc00, acc11 = acc00;
  #pragma unroll 4
  for (int i = 0; i < 16; i++) {
    int off = i * 32;
    bf16x8 a0 = *(const bf16x8*)(Ap0 + off);
    bf16x8 a1 = *(const bf16x8*)(Ap1 + off);
    bf16x8 b0 = *(const bf16x8*)(Bp0 + off);
    bf16x8 b1 = *(const bf16x8*)(Bp1 + off);
    acc00 = __builtin_amdgcn_mfma_f32_16x16x32_bf16(a0, b0, acc00, 0, 0, 0);
    acc01 = __builtin_amdgcn_mfma_f32_16x16x32_bf16(a0, b1, acc01, 0, 0, 0);
    acc10 = __builtin_amdgcn_mfma_f32_16x16x32_bf16(a1, b0, acc10, 0, 0, 0);
    acc11 = __builtin_amdgcn_mfma_f32_16x16x32_bf16(a1, b1, acc11, 0, 0, 0);
  }
  // C/D layout: col = lane&15, row = (lane>>4)*4 + reg   [m89-verified]
  float* Cb = Cp + ((size_t)kc << 19);   // kc * QDIM * SDIM
  int r0 = (lane >> 4) * 4;
  int c0 = lane & 15;
  #pragma unroll
  for (int r = 0; r < 4; r++) {
    Cb[(size_t)(m0 + r0 + r) * SDIM + n0 + c0]           = acc00[r];
    Cb[(size_t)(m0 + r0 + r) * SDIM + n0 + 16 + c0]      = acc01[r];
    Cb[(size_t)(m0 + 16 + r0 + r) * SDIM + n0 + c0]      = acc10[r];
    Cb[(size_t)(m0 + 16 + r0 + r) * SDIM + n0 + 16 + c0] = acc11[r];
  }
}

// ---------------- K4: reduce partials, apply leftv (fp32), diag mask, C + stats
__global__ void k_reduce_stats(const float* __restrict__ Cp,
                               const int* __restrict__ qid, const int* __restrict__ sid,
                               const float* __restrict__ rowsum,
                               float* __restrict__ C, double* __restrict__ stats) {
  __shared__ float r1[256], r2[256]; __shared__ int rc[256];
  int t = threadIdx.x;
  int idx4 = blockIdx.x * 256 + t;                 // float4 index, 512 blocks
  const float4* Cp4 = (const float4*)Cp;
  const int STRIDE4 = QDIM * SDIM / 4;             // 131072
  float4 v = Cp4[idx4];
  float4 v1 = Cp4[idx4 + STRIDE4];
  float4 v2 = Cp4[idx4 + 2 * STRIDE4];
  float4 v3 = Cp4[idx4 + 3 * STRIDE4];
  v.x += v1.x + v2.x + v3.x; v.y += v1.y + v2.y + v3.y;
  v.z += v1.z + v2.z + v3.z; v.w += v1.w + v2.w + v3.w;
  int base = idx4 * 4;
  int q = base >> 9;
  int s0 = base & (SDIM - 1);
  int qv = qid[q];
  float lq = guard_rsqrt(rowsum[qv]);
  int4 sv = *(const int4*)(sid + s0);
  v.x *= lq; v.y *= lq; v.z *= lq; v.w *= lq;
  if (sv.x == qv) v.x = 0.f;
  if (sv.y == qv) v.y = 0.f;
  if (sv.z == qv) v.z = 0.f;
  if (sv.w == qv) v.w = 0.f;
  ((float4*)C)[idx4] = v;
  float s = 0.f, s2 = 0.f; int c = 0;
  float* vp = (float*)&v;
  #pragma unroll
  for (int p = 0; p < 4; p++) {
    float x = vp[p];
    if (x > 0.f) { s += x; s2 += x * x; c++; }
  }
  r1[t] = s; r2[t] = s2; rc[t] = c; __syncthreads();
  for (int st = 128; st > 0; st >>= 1) {
    if (t < st) { r1[t] += r1[t+st]; r2[t] += r2[t+st]; rc[t] += rc[t+st]; }
    __syncthreads();
  }
  if (t == 0) {
    atomicAdd(&stats[0], (double)r1[0]);
    atomicAdd(&stats[1], (double)r2[0]);
    atomicAdd(&stats[2], (double)rc[0]);
  }
}

// ---------------- K5: global calib + row-normalize (one block per query row)
__global__ void k_final(const float* __restrict__ C, const double* __restrict__ stats,
                        const float* __restrict__ gw, const float* __restrict__ gb,
                        float* __restrict__ out) {
  __shared__ float red[256];
  int q = blockIdx.x, t = threadIdx.x;
  double mean_d = stats[0] / stats[2];
  double var_d = stats[1] / stats[2] - mean_d * mean_d;
  float mean = (float)mean_d;
  float invstd = (float)(1.0 / sqrt(var_d));
  float w0 = gw[0], w1 = gw[1], w2 = gw[2], w3 = gw[3], w4 = gw[4], bb = gb[0];
  float vals[2]; float rs = 0.f;
  #pragma unroll
  for (int p = 0; p < 2; p++) {
    int s = t + p * 256;
    float x = C[(size_t)q * SDIM + s];
    float v = 0.f;
    if (x > 0.f) {
      float gn = (x - mean) * invstd;
      float m = fabsf(gn);
      float sgnsq = (m > 0.f) ? (gn / m) * sqrtf(m) : 0.f;  // sign(gn)*sqrt(|gn|)
      float acc = w0 * gn + w1 * sgnsq;
      float gm = gn * m; acc += w2 * gm;   // gn*|gn|
      gm *= m;           acc += w3 * gm;   // gn*|gn|^2
      gm *= m;           acc += w4 * gm;   // gn*|gn|^3
      acc += bb;
      v = (acc > 0.f ? acc : __expf(acc) - 1.f) + 1.f;  // elu + 1
    }
    vals[p] = v; rs += v;
  }
  red[t] = rs; __syncthreads();
  for (int st = 128; st > 0; st >>= 1) { if (t < st) red[t] += red[t+st]; __syncthreads(); }
  float tot = red[0];
  float inv = tot > 0.f ? 1.0f / tot : 0.f;   // divide_no_nan
  #pragma unroll
  for (int p = 0; p < 2; p++) {
    int s = t + p * 256;
    out[(size_t)q * SDIM + s] = vals[p] * inv;
  }
}

extern "C" void kernel_launch(void* const* d_in, const int* in_sizes, int n_in,
                              void* d_out, int out_size, void* d_ws, size_t ws_size,
                              hipStream_t stream) {
  const float* graph    = (const float*)d_in[0];
  const float* calib_w  = (const float*)d_in[1];
  const float* global_w = (const float*)d_in[2];
  const float* global_b = (const float*)d_in[3];
  const float* col_w    = (const float*)d_in[4];
  const int*   qid      = (const int*)d_in[5];
  const int*   sid      = (const int*)d_in[6];
  float* out = (float*)d_out;

  char* ws = (char*)d_ws;
  // zero-region (one tiny memset): colsum | rowsum | stats
  float*  colsum = (float*)(ws + 0);                 // 2048 f = 8 KiB
  float*  rowsum = (float*)(ws + 8192);              // 2048 f = 8 KiB
  double* stats  = (double*)(ws + 16384);            // 3 d
  unsigned short* g0bf = (unsigned short*)(ws + 65536);                  // N*N bf16 = 8 MiB
  unsigned short* Bt   = (unsigned short*)(ws + 65536 + 8388608);        // S*N bf16 = 2 MiB
  float*  Cp     = (float*)(ws + 65536 + 8388608 + 2097152);             // 4*Q*S f = 8 MiB
  float*  C      = (float*)(ws + 65536 + 8388608 + 2097152 + 8388608);   // Q*S f = 2 MiB

  hipMemsetAsync(ws, 0, 16448, stream);

  k_calib<<<NDIM / 4, 256, 0, stream>>>(graph, calib_w, g0bf, rowsum, colsum);
  k_gatherBt<<<dim3(NDIM / GT_TK, SDIM / GT_TS), 512, 0, stream>>>(g0bf, sid, rowsum, colsum, col_w, Bt);
  k_mfma<<<dim3(SDIM / 64, QDIM / 64, 4), 256, 0, stream>>>(g0bf, Bt, qid, Cp);
  k_reduce_stats<<<QDIM * SDIM / 1024, 256, 0, stream>>>(Cp, qid, sid, rowsum, C, stats);
  k_final<<<QDIM, 256, 0, stream>>>(C, stats, global_w, global_b, out);
}